// Round 8
// baseline (239.579 us; speedup 1.0000x reference)
//
#include <hip/hip_runtime.h>

#define B_ROWS 8192
#define IN_DIM 512
#define OUT_DIM 512
#define NDEG 8                 // DEGREE+1
#define KDIM (IN_DIM * NDEG)   // 4096
#define ZS 2                   // K-split slices
#define NKT 32                 // K-tiles (of 64) per z-slice

typedef short bf16x8 __attribute__((ext_vector_type(8)));
typedef float f32x4  __attribute__((ext_vector_type(4)));

__device__ __forceinline__ unsigned short f2bf(float f) {
  unsigned u = __float_as_uint(f);
  u += 0x7fffu + ((u >> 16) & 1u);   // RNE
  return (unsigned short)(u >> 16);
}

__device__ __forceinline__ void laguerre8(float t, float* L) {
  L[0] = 1.0f;
  L[1] = 1.5f - t;
#pragma unroll
  for (int k = 2; k < NDEG; ++k)
    L[k] = ((2.0f * (float)k - 0.5f - t) * L[k - 1] -
            ((float)k - 0.5f) * L[k - 2]) * (1.0f / (float)k);
}

__device__ __forceinline__ float ftanh(float x) {
  float e2 = __expf(2.0f * x);
  return (e2 - 1.0f) * (1.0f / (e2 + 1.0f));
}

__device__ __forceinline__ uint4 bpack(float xv) {
  float L[NDEG];
  laguerre8(ftanh(xv), L);
  uint4 v;
  v.x = (unsigned)f2bf(L[0]) | ((unsigned)f2bf(L[1]) << 16);
  v.y = (unsigned)f2bf(L[2]) | ((unsigned)f2bf(L[3]) << 16);
  v.z = (unsigned)f2bf(L[4]) | ((unsigned)f2bf(L[5]) << 16);
  v.w = (unsigned)f2bf(L[6]) | ((unsigned)f2bf(L[7]) << 16);
  return v;
}

// Brick layout (A and B identical; verified conflicts==0 in rounds 5/6):
// 128-row x 64-k half-tiles of 16B chunks:
//   chunk = (rowblk*64 + ktile)*1024 + (rb>>6)*512 + (rb&63)*8 + (c ^ (rb&7))

// ---- pass 1: A bricks (coalesced: 1 block per brick) | Bt bricks --------------
__global__ void prep_kernel(const float* __restrict__ x, const float* __restrict__ cf,
                            unsigned short* __restrict__ A, unsigned short* __restrict__ Bt) {
  const int g = blockIdx.x, tid = threadIdx.x;
  if (g < 4096) {                       // A brick (h = rowblk, t = ktile)
    const int h = g >> 6, t = g & 63;
    uint4* dst = (uint4*)A + (size_t)g * 1024;
#pragma unroll
    for (int q = 0; q < 4; ++q) {
      int v = q * 256 + tid;            // chunk_local: writes fully contiguous
      int rb = ((v >> 9) << 6) | ((v >> 3) & 63);
      int c = (v & 7) ^ (rb & 7);
      float xv = x[(size_t)(h * 128 + rb) * 512 + t * 8 + c];
      dst[v] = bpack(xv);
    }
  } else {                              // coeff -> Bt brick (r7 code, verified)
    int idx = (g - 4096) * 256 + tid;   // i*512 + o
    int i = idx >> 9, o = idx & 511;
    const float4* cp = (const float4*)(cf + (size_t)idx * 8);
    float4 c0 = cp[0], c1 = cp[1];
    uint4 v;
    v.x = (unsigned)f2bf(c0.x) | ((unsigned)f2bf(c0.y) << 16);
    v.y = (unsigned)f2bf(c0.z) | ((unsigned)f2bf(c0.w) << 16);
    v.z = (unsigned)f2bf(c1.x) | ((unsigned)f2bf(c1.y) << 16);
    v.w = (unsigned)f2bf(c1.z) | ((unsigned)f2bf(c1.w) << 16);
    int h = o >> 7, rb = o & 127, t = i >> 3, c = i & 7;
    size_t chunk = ((size_t)(h * 64 + t)) * 1024 + (rb >> 6) * 512 + (rb & 63) * 8 + (c ^ (rb & 7));
    ((uint4*)Bt)[chunk] = v;
  }
}

// ---- pass 2: GEMM 128x128, z=2, 2 blocks/CU, counted-vmcnt 2-buf pipeline ------
// 8 waves (2m x 4n), wave-tile 64x32, acc[4][2]. LDS 64 KB.
// Last z-block per (My,n) sums both partials -> f32 out (reduce folded in).

#define VM(N) { asm volatile("s_waitcnt vmcnt(" #N ")" ::: "memory");  \
                __builtin_amdgcn_sched_barrier(0); }
#define GL16(s, d)                                                      \
  __builtin_amdgcn_global_load_lds(                                     \
      (const __attribute__((address_space(1))) unsigned int*)(s),       \
      (__attribute__((address_space(3))) unsigned int*)(d), 16, 0, 0)

__global__ __launch_bounds__(512, 4) void gemm_kernel(const unsigned short* __restrict__ A,
                                                      const unsigned short* __restrict__ Bt,
                                                      unsigned short* __restrict__ P,
                                                      float* __restrict__ out,
                                                      unsigned int* __restrict__ cnt) {
  __shared__ __align__(16) unsigned short lds[32768];   // 64 KB: A0|A1|B0|B1 (16KB each)
  __shared__ int lastFlag;

  const int tid = threadIdx.x;
  const int lane = tid & 63;
  const int w = tid >> 6;
  const int wm = w >> 2, wn = w & 3;      // 2m x 4n, wave-tile 64x32

  // bijective decode; A-panel sharers (same My: all n,z) co-XCD
  const int g = blockIdx.x;               // 0..511
  const int slot = g >> 3, xcd = g & 7;
  const int My = ((slot & 7) << 3) | xcd; // 0..63
  const int n = (slot >> 3) & 3;          // 0..3
  const int z = slot >> 5;                // 0..1

  const uint4* Ag = (const uint4*)A;
  const uint4* Bg = (const uint4*)Bt;

  const int arow = lane & 15, hi = lane >> 4;
  const int e = (hi ^ (arow & 7)) * 8;    // swizzled chunk offset (shorts)

  f32x4 zero = {0.f, 0.f, 0.f, 0.f};
  f32x4 acc[4][2];
#pragma unroll
  for (int m4 = 0; m4 < 4; ++m4)
#pragma unroll
    for (int ni = 0; ni < 2; ++ni) acc[m4][ni] = zero;

  auto STAGE = [&](int t, int buf) {      // 4 gl_lds/wave: A 2 + B 2
    const int tg = z * NKT + t;
    const uint4* a = Ag + ((size_t)(My * 64 + tg)) * 1024 + w * 128 + lane;
    unsigned short* dA = lds + buf * 8192 + w * 1024;
    GL16(a, dA); GL16(a + 64, dA + 512);
    const uint4* b = Bg + ((size_t)(n * 64 + tg)) * 1024 + w * 128 + lane;
    unsigned short* dB = lds + 16384 + buf * 8192 + w * 1024;
    GL16(b, dB); GL16(b + 64, dB + 512);
  };

  auto COMPUTE = [&](int buf) {
    const unsigned short* Ab = lds + buf * 8192 + wm * 4096 + arow * 64;
    const unsigned short* Bb = lds + 16384 + buf * 8192 + (wn >> 1) * 4096
                               + (wn & 1) * 2048 + arow * 64;
#pragma unroll
    for (int ks = 0; ks < 2; ++ks) {
      const int o = e ^ (ks * 32);
      bf16x8 af[4], bfr[2];
#pragma unroll
      for (int m4 = 0; m4 < 4; ++m4) af[m4] = *(const bf16x8*)(Ab + m4 * 1024 + o);
#pragma unroll
      for (int ni = 0; ni < 2; ++ni) bfr[ni] = *(const bf16x8*)(Bb + ni * 1024 + o);
      __builtin_amdgcn_s_setprio(1);
#pragma unroll
      for (int m4 = 0; m4 < 4; ++m4)
#pragma unroll
        for (int ni = 0; ni < 2; ++ni)
          acc[m4][ni] = __builtin_amdgcn_mfma_f32_16x16x32_bf16(af[m4], bfr[ni], acc[m4][ni], 0, 0, 0);
      __builtin_amdgcn_s_setprio(0);
    }
  };

  // ---- prologue ----
  STAGE(0, 0); STAGE(1, 1);
  VM(4);                                   // tile0 landed (tile1 in flight)
  __builtin_amdgcn_s_barrier();

  // ---- main loop ----
#pragma unroll 2
  for (int t = 0; t < NKT - 2; ++t) {
    const int cur = t & 1;
    COMPUTE(cur);
    asm volatile("s_waitcnt lgkmcnt(0)" ::: "memory");   // my reads of buf[cur] done
    __builtin_amdgcn_sched_barrier(0);
    __builtin_amdgcn_s_barrier();                        // all waves done reading
    STAGE(t + 2, cur);                                   // overwrite with t+2
    VM(4);                                               // t+1 landed (t+2 in flight)
    __builtin_amdgcn_s_barrier();
  }
  // ---- peel t=30,31 ----
  COMPUTE(0);
  VM(0);                                   // tile31 landed
  __builtin_amdgcn_s_barrier();
  COMPUTE(1);
  __syncthreads();                         // drain before LDS reuse

  // ---- epilogue: per-wave bf16 bounce -> coalesced P stores (r6 pattern) ----
  unsigned short* W = lds + w * 4096;      // 64 rows x 64 shorts (cols 0..31 used)
#pragma unroll
  for (int m4 = 0; m4 < 4; ++m4)
#pragma unroll
    for (int ni = 0; ni < 2; ++ni) {
      int col = ni * 16 + arow;
      int c8 = col >> 3, cpos = col & 7;
#pragma unroll
      for (int r = 0; r < 4; ++r) {
        int row = m4 * 16 + hi * 4 + r;
        W[row * 64 + ((c8 ^ (row & 7)) << 3) + cpos] = f2bf(acc[m4][ni][r]);
      }
    }
#pragma unroll
  for (int it = 0; it < 4; ++it) {
    int row = it * 16 + (lane >> 2), cc2 = lane & 3;
    uint4 v = *(uint4*)&W[row * 64 + ((cc2 ^ (row & 7)) << 3)];
    size_t pr = (size_t)z * ((size_t)B_ROWS * OUT_DIM)
              + (size_t)(My * 128 + wm * 64 + row) * 512 + n * 128 + wn * 32 + cc2 * 8;
    *(uint4*)&P[pr] = v;
  }

  // ---- folded reduce: last z-block of (My,n) sums both partials -> f32 out ----
  __threadfence();                         // release my P writes (device scope)
  if (tid == 0)
    lastFlag = (atomicAdd(&cnt[My * 4 + n], 1u) == 1u);
  __syncthreads();
  if (lastFlag) {
    __threadfence();                       // acquire other block's P
    const size_t ss = (size_t)B_ROWS * OUT_DIM;
#pragma unroll
    for (int q = 0; q < 4; ++q) {
      int el = q * 512 + tid;              // 2048 chunks of 8 els (128x128 tile)
      int row = el >> 4, cc = el & 15;
      size_t off = (size_t)(My * 128 + row) * 512 + n * 128 + cc * 8;
      uint4 a = *(const uint4*)&P[off];
      uint4 b = *(const uint4*)&P[off + ss];
      unsigned qa[4] = {a.x, a.y, a.z, a.w}, qb[4] = {b.x, b.y, b.z, b.w};
      float s[8];
#pragma unroll
      for (int j = 0; j < 4; ++j) {
        s[2 * j]     = __uint_as_float((qa[j] & 0xffffu) << 16) +
                       __uint_as_float((qb[j] & 0xffffu) << 16);
        s[2 * j + 1] = __uint_as_float(qa[j] & 0xffff0000u) +
                       __uint_as_float(qb[j] & 0xffff0000u);
      }
      float4 f0 = {s[0], s[1], s[2], s[3]}, f1 = {s[4], s[5], s[6], s[7]};
      *(float4*)&out[off]     = f0;
      *(float4*)&out[off + 4] = f1;
    }
  }
}

// ---- fallback -------------------------------------------------------------------
__global__ void naive_kernel(const float* __restrict__ x, const float* __restrict__ c,
                             float* __restrict__ out) {
  __shared__ float bas[IN_DIM * NDEG];
  int b = blockIdx.x;
  for (int i = threadIdx.x; i < IN_DIM; i += 256) {
    float t = tanhf(x[(size_t)b * IN_DIM + i]);
    float L[NDEG];
    laguerre8(t, L);
#pragma unroll
    for (int d = 0; d < NDEG; ++d) bas[i * NDEG + d] = L[d];
  }
  __syncthreads();
  for (int o = threadIdx.x; o < OUT_DIM; o += 256) {
    float acc = 0.f;
    for (int i = 0; i < IN_DIM; ++i) {
      const float* cp = c + ((size_t)i * OUT_DIM + o) * NDEG;
#pragma unroll
      for (int d = 0; d < NDEG; ++d) acc += bas[i * NDEG + d] * cp[d];
    }
    out[(size_t)b * OUT_DIM + o] = acc;
  }
}

extern "C" void kernel_launch(void* const* d_in, const int* in_sizes, int n_in,
                              void* d_out, int out_size, void* d_ws, size_t ws_size,
                              hipStream_t stream) {
  const float* x    = (const float*)d_in[0];
  const float* coef = (const float*)d_in[1];
  float* out = (float*)d_out;

  const size_t A_B   = (size_t)B_ROWS * KDIM * 2;        // 64 MiB
  const size_t P_B   = (size_t)ZS * B_ROWS * OUT_DIM * 2;// 16 MiB
  const size_t BT_B  = (size_t)OUT_DIM * KDIM * 2;       // 4 MiB
  const size_t CNT_B = 1024;

  if (ws_size >= A_B + P_B + BT_B + CNT_B) {   // 84 MiB (>=100 MiB proven earlier)
    unsigned short* Abuf = (unsigned short*)d_ws;
    unsigned short* Pp   = (unsigned short*)((char*)d_ws + A_B);
    unsigned short* Bt   = (unsigned short*)((char*)d_ws + A_B + P_B);
    unsigned int*   cnt  = (unsigned int*)((char*)d_ws + A_B + P_B + BT_B);
    hipMemsetAsync(cnt, 0, CNT_B, stream);
    prep_kernel<<<4096 + 1024, 256, 0, stream>>>(x, coef, Abuf, Bt);
    gemm_kernel<<<512, 512, 0, stream>>>(Abuf, Bt, Pp, out, cnt);
  } else {
    naive_kernel<<<B_ROWS, 256, 0, stream>>>(x, coef, out);
  }
}

// Round 9
// 133.386 us; speedup vs baseline: 1.7961x; 1.7961x over previous
//
#include <hip/hip_runtime.h>

#define B_ROWS 8192
#define IN_DIM 512
#define OUT_DIM 512
#define NDEG 8                 // DEGREE+1
#define KDIM (IN_DIM * NDEG)   // 4096
#define ZSLICES 4
#define NKT 16                 // K-tiles (of 64) per z-slice

typedef short bf16x8 __attribute__((ext_vector_type(8)));
typedef float f32x4  __attribute__((ext_vector_type(4)));

__device__ __forceinline__ unsigned short f2bf(float f) {
  unsigned u = __float_as_uint(f);
  u += 0x7fffu + ((u >> 16) & 1u);   // RNE
  return (unsigned short)(u >> 16);
}

__device__ __forceinline__ void laguerre8(float t, float* L) {
  L[0] = 1.0f;
  L[1] = 1.5f - t;
#pragma unroll
  for (int k = 2; k < NDEG; ++k)
    L[k] = ((2.0f * (float)k - 0.5f - t) * L[k - 1] -
            ((float)k - 0.5f) * L[k - 2]) * (1.0f / (float)k);
}

__device__ __forceinline__ float ftanh(float x) {
  float e2 = __expf(2.0f * x);
  return (e2 - 1.0f) * (1.0f / (e2 + 1.0f));
}

__device__ __forceinline__ uint4 bpack(float xv) {
  float L[NDEG];
  laguerre8(ftanh(xv), L);
  uint4 v;
  v.x = (unsigned)f2bf(L[0]) | ((unsigned)f2bf(L[1]) << 16);
  v.y = (unsigned)f2bf(L[2]) | ((unsigned)f2bf(L[3]) << 16);
  v.z = (unsigned)f2bf(L[4]) | ((unsigned)f2bf(L[5]) << 16);
  v.w = (unsigned)f2bf(L[6]) | ((unsigned)f2bf(L[7]) << 16);
  return v;
}

// Brick layout (A and B identical; SQ_LDS_BANK_CONFLICT==0 verified r5/r6):
// 128-row x 64-k half-tiles of 16B chunks:
//   chunk = (rowblk*64 + ktile)*1024 + (rb>>6)*512 + (rb&63)*8 + (c ^ (rb&7))

// ---- pass 1: A bricks (coalesced, 1 block/brick) | Bt bricks | cnt zero --------
__global__ void prep_kernel(const float* __restrict__ x, const float* __restrict__ cf,
                            unsigned short* __restrict__ A, unsigned short* __restrict__ Bt,
                            unsigned int* __restrict__ cnt) {
  const int g = blockIdx.x, tid = threadIdx.x;
  if (g < 4096) {                       // A brick (h = rowblk, t = ktile)
    const int h = g >> 6, t = g & 63;
    uint4* dst = (uint4*)A + (size_t)g * 1024;
#pragma unroll
    for (int q = 0; q < 4; ++q) {
      int v = q * 256 + tid;            // chunk_local: writes fully contiguous
      int rb = ((v >> 9) << 6) | ((v >> 3) & 63);
      int c = (v & 7) ^ (rb & 7);
      float xv = x[(size_t)(h * 128 + rb) * 512 + t * 8 + c];
      dst[v] = bpack(xv);
    }
  } else if (g < 4096 + 1024) {         // coeff -> Bt brick (verified r6-r8)
    int idx = (g - 4096) * 256 + tid;   // i*512 + o
    int i = idx >> 9, o = idx & 511;
    const float4* cp = (const float4*)(cf + (size_t)idx * 8);
    float4 c0 = cp[0], c1 = cp[1];
    uint4 v;
    v.x = (unsigned)f2bf(c0.x) | ((unsigned)f2bf(c0.y) << 16);
    v.y = (unsigned)f2bf(c0.z) | ((unsigned)f2bf(c0.w) << 16);
    v.z = (unsigned)f2bf(c1.x) | ((unsigned)f2bf(c1.y) << 16);
    v.w = (unsigned)f2bf(c1.z) | ((unsigned)f2bf(c1.w) << 16);
    int h = o >> 7, rb = o & 127, t = i >> 3, c = i & 7;
    size_t chunk = ((size_t)(h * 64 + t)) * 1024 + (rb >> 6) * 512 + (rb & 63) * 8 + (c ^ (rb & 7));
    ((uint4*)Bt)[chunk] = v;
  } else {                              // zero the finisher counters
    if (tid < 64) cnt[tid] = 0;
  }
}

// ---- pass 2: GEMM 256x256, 8-phase schedule (r6 verbatim) + folded reduce ------
#define PH(buf, mq, ks, LOADBF, VMW, ...)                                          \
  {                                                                                \
    const unsigned short* Ab_ = lds + (buf)*16384 + wm*8192 + (mq)*4096 + arow*64; \
    _Pragma("unroll") for (int m4 = 0; m4 < 4; ++m4)                               \
      af[m4] = *(const bf16x8*)(Ab_ + m4*1024 + (e ^ ((ks)*32)));                  \
    if (LOADBF) {                                                                  \
      const unsigned short* Bb_ = lds + 32768 + (buf)*16384 + (wn>>1)*8192         \
                                  + (wn&1)*4096 + arow*64;                         \
      _Pragma("unroll") for (int ni = 0; ni < 4; ++ni)                             \
        bfr[ni] = *(const bf16x8*)(Bb_ + ni*1024 + (e ^ ((ks)*32)));               \
    }                                                                              \
    __VA_ARGS__;                                                                   \
    __builtin_amdgcn_s_barrier();                                                  \
    asm volatile("s_waitcnt lgkmcnt(0)" ::: "memory");                             \
    __builtin_amdgcn_sched_barrier(0);                                             \
    __builtin_amdgcn_s_setprio(1);                                                 \
    _Pragma("unroll") for (int m4 = 0; m4 < 4; ++m4)                               \
      _Pragma("unroll") for (int ni = 0; ni < 4; ++ni)                             \
        acc[(mq)*4+m4][ni] = __builtin_amdgcn_mfma_f32_16x16x32_bf16(              \
            af[m4], bfr[ni], acc[(mq)*4+m4][ni], 0, 0, 0);                         \
    __builtin_amdgcn_s_setprio(0);                                                 \
    if ((VMW) == 1) { asm volatile("s_waitcnt vmcnt(2)" ::: "memory");             \
                      __builtin_amdgcn_sched_barrier(0); }                         \
    if ((VMW) == 2) { asm volatile("s_waitcnt vmcnt(0)" ::: "memory");             \
                      __builtin_amdgcn_sched_barrier(0); }                         \
    __builtin_amdgcn_s_barrier();                                                  \
  }

__global__ __launch_bounds__(512, 2) void gemm_kernel(const unsigned short* __restrict__ A,
                                                      const unsigned short* __restrict__ Bt,
                                                      unsigned short* __restrict__ P,
                                                      float* __restrict__ out,
                                                      unsigned int* __restrict__ cnt) {
  __shared__ unsigned short lds[65536];   // 128 KB: A ring 64 KB | B ring 64 KB
  __shared__ int lastFlag;

  const int tid = threadIdx.x;
  const int lane = tid & 63;
  const int w = tid >> 6;
  const int wm = w >> 2, wn = w & 3;

  // bijective decode, A-panel sharers co-XCD
  const int g = blockIdx.x;               // 0..255
  const int j0 = g >> 3, xx = g & 7;
  const int My = ((j0 >> 3) << 3) | xx;   // 0..31
  const int n = (j0 >> 2) & 1;            // 0..1
  const int z = j0 & 3;                   // 0..3

  const uint4* Ag = (const uint4*)A;
  const uint4* Bg = (const uint4*)Bt;

  const int arow = lane & 15, hi = lane >> 4;
  const int e = (hi ^ (arow & 7)) * 8;    // swizzled chunk offset (shorts)

  f32x4 zero = {0.f, 0.f, 0.f, 0.f};
  f32x4 acc[8][4];
#pragma unroll
  for (int mi = 0; mi < 8; ++mi)
#pragma unroll
    for (int ni = 0; ni < 4; ++ni) acc[mi][ni] = zero;

  // stage one 16KB half-tile: 2 gl_lds per wave (linear chunk->chunk)
  auto STAGE_H = [&](int isB, int h, int tile, int buf) {
    const uint4* src = isB ? Bg : Ag;
    const int rowblk = (isB ? n * 2 : My * 2) + h;
    const size_t c0 = ((size_t)(rowblk * 64 + z * NKT + tile)) * 1024 + w * 64 + lane;
    unsigned short* d = lds + isB * 32768 + buf * 16384 + h * 8192 + w * 512;
    __builtin_amdgcn_global_load_lds(
        (const __attribute__((address_space(1))) unsigned int*)(src + c0),
        (__attribute__((address_space(3))) unsigned int*)d, 16, 0, 0);
    __builtin_amdgcn_global_load_lds(
        (const __attribute__((address_space(1))) unsigned int*)(src + c0 + 512),
        (__attribute__((address_space(3))) unsigned int*)(d + 4096), 16, 0, 0);
  };

  bf16x8 af[4], bfr[4];

  // ---- prologue: tile0 (4 halves) -> buf0, B0(tile1) -> buf1; 10 loads ----
  STAGE_H(0, 0, 0, 0); STAGE_H(0, 1, 0, 0);
  STAGE_H(1, 0, 0, 0); STAGE_H(1, 1, 0, 0);
  STAGE_H(1, 0, 1, 1);
  asm volatile("s_waitcnt vmcnt(2)" ::: "memory");   // tile0 landed; B0(t1) in flight
  __builtin_amdgcn_sched_barrier(0);
  __builtin_amdgcn_s_barrier();

  // ---- main loop: iters 0..6, tiles (2it, 2it+1); stage t1-rest, t2, B0(t3) ----
  for (int it = 0; it < 7; ++it) {
    const int t1 = 2 * it + 1, t2 = 2 * it + 2, t3 = 2 * it + 3;
    PH(0, 0, 0, 1, 0, STAGE_H(1, 1, t1, 1));   // p0: +bf(ks0); stage B1(t1)
    PH(0, 1, 0, 0, 0, STAGE_H(0, 0, t1, 1));   // p1: stage A0(t1)
    PH(0, 0, 1, 1, 0, STAGE_H(0, 1, t1, 1));   // p2: +bf(ks1); stage A1(t1)
    PH(0, 1, 1, 0, 1, STAGE_H(1, 0, t2, 0));   // p3: stage B0(t2); vmcnt(2)
    PH(1, 0, 0, 1, 0, STAGE_H(0, 0, t2, 0));   // p4: stage A0(t2)
    PH(1, 1, 0, 0, 0, STAGE_H(0, 1, t2, 0));   // p5: stage A1(t2)
    PH(1, 0, 1, 1, 0, STAGE_H(1, 1, t2, 0));   // p6: stage B1(t2)
    PH(1, 1, 1, 0, 1, STAGE_H(1, 0, t3, 1));   // p7: stage B0(t3); vmcnt(2)
  }
  // ---- peeled iter 7: tiles 14,15; finish staging t1=15, no further stages ----
  PH(0, 0, 0, 1, 0, STAGE_H(1, 1, 15, 1));
  PH(0, 1, 0, 0, 0, STAGE_H(0, 0, 15, 1));
  PH(0, 0, 1, 1, 0, STAGE_H(0, 1, 15, 1));
  PH(0, 1, 1, 0, 2, (void)0);                  // vmcnt(0): tile15 fully landed
  PH(1, 0, 0, 1, 0, (void)0);
  PH(1, 1, 0, 0, 0, (void)0);
  PH(1, 0, 1, 1, 0, (void)0);
  PH(1, 1, 1, 0, 0, (void)0);

  // ---- epilogue: bf16 via per-wave LDS bounce (swizzled) -> uint4 line stores ----
  unsigned short* W = lds + w * 8192;    // 128 rows x 64 shorts per wave
#pragma unroll
  for (int mi = 0; mi < 8; ++mi)
#pragma unroll
    for (int ni = 0; ni < 4; ++ni) {
      int col = ni * 16 + arow;
      int c8 = col >> 3, cpos = col & 7;
#pragma unroll
      for (int r = 0; r < 4; ++r) {
        int row = mi * 16 + hi * 4 + r;
        W[row * 64 + ((c8 ^ (row & 7)) << 3) + cpos] = f2bf(acc[mi][ni][r]);
      }
    }
  const int rr = lane >> 3, cc = lane & 7;
#pragma unroll
  for (int it = 0; it < 16; ++it) {
    int row = it * 8 + rr;
    uint4 v = *(uint4*)&W[row * 64 + ((cc ^ (row & 7)) << 3)];
    size_t pr = ((size_t)z * B_ROWS + My * 256 + wm * 128 + row) * 512 + n * 256 + wn * 64 + cc * 8;
    *(uint4*)&P[pr] = v;
  }

  // ---- folded reduce: 4th z-arriver per (My,n) sums partials -> f32 out ----
  __syncthreads();                         // drains P stores (vmcnt 0) for all waves
  __threadfence();                         // release (device scope, cross-XCD safe)
  if (tid == 0)
    lastFlag = ((int)atomicAdd(&cnt[My * 2 + n], 1u) == ZSLICES - 1);
  __syncthreads();
  if (lastFlag) {
    __threadfence();                       // acquire
    const size_t ss = (size_t)B_ROWS * OUT_DIM;
#pragma unroll
    for (int q = 0; q < 16; ++q) {
      int el = q * 512 + tid;              // 8192 chunks of 8 = 256x256 tile
      int row = el >> 5, cc2 = el & 31;
      size_t off = (size_t)(My * 256 + row) * 512 + n * 256 + cc2 * 8;
      float s[8] = {0, 0, 0, 0, 0, 0, 0, 0};
#pragma unroll
      for (int zz = 0; zz < ZSLICES; ++zz) {
        uint4 v = *(const uint4*)&P[off + zz * ss];
        unsigned qv[4] = {v.x, v.y, v.z, v.w};
#pragma unroll
        for (int j = 0; j < 4; ++j) {
          s[2 * j]     += __uint_as_float((qv[j] & 0xffffu) << 16);
          s[2 * j + 1] += __uint_as_float(qv[j] & 0xffff0000u);
        }
      }
      float4 f0 = {s[0], s[1], s[2], s[3]}, f1 = {s[4], s[5], s[6], s[7]};
      *(float4*)&out[off]     = f0;
      *(float4*)&out[off + 4] = f1;
    }
  }
}

// ---- fallback -------------------------------------------------------------------
__global__ void naive_kernel(const float* __restrict__ x, const float* __restrict__ c,
                             float* __restrict__ out) {
  __shared__ float bas[IN_DIM * NDEG];
  int b = blockIdx.x;
  for (int i = threadIdx.x; i < IN_DIM; i += 256) {
    float t = tanhf(x[(size_t)b * IN_DIM + i]);
    float L[NDEG];
    laguerre8(t, L);
#pragma unroll
    for (int d = 0; d < NDEG; ++d) bas[i * NDEG + d] = L[d];
  }
  __syncthreads();
  for (int o = threadIdx.x; o < OUT_DIM; o += 256) {
    float acc = 0.f;
    for (int i = 0; i < IN_DIM; ++i) {
      const float* cp = c + ((size_t)i * OUT_DIM + o) * NDEG;
#pragma unroll
      for (int d = 0; d < NDEG; ++d) acc += bas[i * NDEG + d] * cp[d];
    }
    out[(size_t)b * OUT_DIM + o] = acc;
  }
}

extern "C" void kernel_launch(void* const* d_in, const int* in_sizes, int n_in,
                              void* d_out, int out_size, void* d_ws, size_t ws_size,
                              hipStream_t stream) {
  const float* x    = (const float*)d_in[0];
  const float* coef = (const float*)d_in[1];
  float* out = (float*)d_out;

  const size_t A_B  = (size_t)B_ROWS * KDIM * 2;              // 64 MiB
  const size_t P_B  = (size_t)ZSLICES * B_ROWS * OUT_DIM * 2; // 32 MiB
  const size_t BT_B = (size_t)OUT_DIM * KDIM * 2;             // 4 MiB

  if (ws_size >= A_B + P_B + BT_B + 256) {   // 100 MiB — proven rounds 3-6
    unsigned short* Abuf = (unsigned short*)d_ws;
    unsigned short* Pp   = (unsigned short*)((char*)d_ws + A_B);
    unsigned short* Bt   = (unsigned short*)((char*)d_ws + A_B + P_B);
    unsigned int*   cnt  = (unsigned int*)((char*)d_ws + A_B + P_B + BT_B);
    prep_kernel<<<4096 + 1024 + 1, 256, 0, stream>>>(x, coef, Abuf, Bt, cnt);
    gemm_kernel<<<256, 512, 0, stream>>>(Abuf, Bt, Pp, out, cnt);
  } else {
    naive_kernel<<<B_ROWS, 256, 0, stream>>>(x, coef, out);
  }
}

// Round 10
// 73.770 us; speedup vs baseline: 3.2476x; 1.8081x over previous
//
#include <hip/hip_runtime.h>

#define B_ROWS 8192
#define IN_DIM 512
#define OUT_DIM 512
#define NDEG 8                 // DEGREE+1
#define KDIM (IN_DIM * NDEG)   // 4096
#define ZSLICES 4
#define NKT 16                 // K-tiles (of 64) per z-slice

typedef short bf16x8 __attribute__((ext_vector_type(8)));
typedef float f32x4  __attribute__((ext_vector_type(4)));

__device__ __forceinline__ unsigned short f2bf(float f) {
  unsigned u = __float_as_uint(f);
  u += 0x7fffu + ((u >> 16) & 1u);   // RNE
  return (unsigned short)(u >> 16);
}

__device__ __forceinline__ void laguerre8(float t, float* L) {
  L[0] = 1.0f;
  L[1] = 1.5f - t;
#pragma unroll
  for (int k = 2; k < NDEG; ++k)
    L[k] = ((2.0f * (float)k - 0.5f - t) * L[k - 1] -
            ((float)k - 0.5f) * L[k - 2]) * (1.0f / (float)k);
}

__device__ __forceinline__ float ftanh(float x) {
  float e2 = __expf(2.0f * x);
  return (e2 - 1.0f) * (1.0f / (e2 + 1.0f));
}

__device__ __forceinline__ uint4 bpack(float xv) {
  float L[NDEG];
  laguerre8(ftanh(xv), L);
  uint4 v;
  v.x = (unsigned)f2bf(L[0]) | ((unsigned)f2bf(L[1]) << 16);
  v.y = (unsigned)f2bf(L[2]) | ((unsigned)f2bf(L[3]) << 16);
  v.z = (unsigned)f2bf(L[4]) | ((unsigned)f2bf(L[5]) << 16);
  v.w = (unsigned)f2bf(L[6]) | ((unsigned)f2bf(L[7]) << 16);
  return v;
}

// Brick layout (A and B identical; SQ_LDS_BANK_CONFLICT==0 verified r5/r6):
// 128-row x 64-k half-tiles of 16B chunks:
//   chunk = (rowblk*64 + ktile)*1024 + (rb>>6)*512 + (rb&63)*8 + (c ^ (rb&7))

// ---- pass 1: A bricks (coalesced, 1 block/brick — validated r8/r9) | Bt bricks --
__global__ void prep_kernel(const float* __restrict__ x, const float* __restrict__ cf,
                            unsigned short* __restrict__ A, unsigned short* __restrict__ Bt) {
  const int g = blockIdx.x, tid = threadIdx.x;
  if (g < 4096) {                       // A brick (h = rowblk, t = ktile)
    const int h = g >> 6, t = g & 63;
    uint4* dst = (uint4*)A + (size_t)g * 1024;
#pragma unroll
    for (int q = 0; q < 4; ++q) {
      int v = q * 256 + tid;            // chunk_local: writes fully contiguous
      int rb = ((v >> 9) << 6) | ((v >> 3) & 63);
      int c = (v & 7) ^ (rb & 7);
      float xv = x[(size_t)(h * 128 + rb) * 512 + t * 8 + c];
      dst[v] = bpack(xv);
    }
  } else {                              // coeff -> Bt brick (verified r6-r9)
    int idx = (g - 4096) * 256 + tid;   // i*512 + o
    int i = idx >> 9, o = idx & 511;
    const float4* cp = (const float4*)(cf + (size_t)idx * 8);
    float4 c0 = cp[0], c1 = cp[1];
    uint4 v;
    v.x = (unsigned)f2bf(c0.x) | ((unsigned)f2bf(c0.y) << 16);
    v.y = (unsigned)f2bf(c0.z) | ((unsigned)f2bf(c0.w) << 16);
    v.z = (unsigned)f2bf(c1.x) | ((unsigned)f2bf(c1.y) << 16);
    v.w = (unsigned)f2bf(c1.z) | ((unsigned)f2bf(c1.w) << 16);
    int h = o >> 7, rb = o & 127, t = i >> 3, c = i & 7;
    size_t chunk = ((size_t)(h * 64 + t)) * 1024 + (rb >> 6) * 512 + (rb & 63) * 8 + (c ^ (rb & 7));
    ((uint4*)Bt)[chunk] = v;
  }
}

// ---- pass 2: GEMM 256x256, 8-phase schedule (r6 verbatim; best measured) -------
#define PH(buf, mq, ks, LOADBF, VMW, ...)                                          \
  {                                                                                \
    const unsigned short* Ab_ = lds + (buf)*16384 + wm*8192 + (mq)*4096 + arow*64; \
    _Pragma("unroll") for (int m4 = 0; m4 < 4; ++m4)                               \
      af[m4] = *(const bf16x8*)(Ab_ + m4*1024 + (e ^ ((ks)*32)));                  \
    if (LOADBF) {                                                                  \
      const unsigned short* Bb_ = lds + 32768 + (buf)*16384 + (wn>>1)*8192         \
                                  + (wn&1)*4096 + arow*64;                         \
      _Pragma("unroll") for (int ni = 0; ni < 4; ++ni)                             \
        bfr[ni] = *(const bf16x8*)(Bb_ + ni*1024 + (e ^ ((ks)*32)));               \
    }                                                                              \
    __VA_ARGS__;                                                                   \
    __builtin_amdgcn_s_barrier();                                                  \
    asm volatile("s_waitcnt lgkmcnt(0)" ::: "memory");                             \
    __builtin_amdgcn_sched_barrier(0);                                             \
    __builtin_amdgcn_s_setprio(1);                                                 \
    _Pragma("unroll") for (int m4 = 0; m4 < 4; ++m4)                               \
      _Pragma("unroll") for (int ni = 0; ni < 4; ++ni)                             \
        acc[(mq)*4+m4][ni] = __builtin_amdgcn_mfma_f32_16x16x32_bf16(              \
            af[m4], bfr[ni], acc[(mq)*4+m4][ni], 0, 0, 0);                         \
    __builtin_amdgcn_s_setprio(0);                                                 \
    if ((VMW) == 1) { asm volatile("s_waitcnt vmcnt(2)" ::: "memory");             \
                      __builtin_amdgcn_sched_barrier(0); }                         \
    if ((VMW) == 2) { asm volatile("s_waitcnt vmcnt(0)" ::: "memory");             \
                      __builtin_amdgcn_sched_barrier(0); }                         \
    __builtin_amdgcn_s_barrier();                                                  \
  }

__global__ __launch_bounds__(512, 2) void gemm_kernel(const unsigned short* __restrict__ A,
                                                      const unsigned short* __restrict__ Bt,
                                                      unsigned short* __restrict__ P) {
  __shared__ unsigned short lds[65536];   // 128 KB: A ring 64 KB | B ring 64 KB

  const int tid = threadIdx.x;
  const int lane = tid & 63;
  const int w = tid >> 6;
  const int wm = w >> 2, wn = w & 3;

  // bijective decode, A-panel sharers co-XCD
  const int g = blockIdx.x;               // 0..255
  const int j0 = g >> 3, xx = g & 7;
  const int My = ((j0 >> 3) << 3) | xx;   // 0..31
  const int n = (j0 >> 2) & 1;            // 0..1
  const int z = j0 & 3;                   // 0..3

  const uint4* Ag = (const uint4*)A;
  const uint4* Bg = (const uint4*)Bt;

  const int arow = lane & 15, hi = lane >> 4;
  const int e = (hi ^ (arow & 7)) * 8;    // swizzled chunk offset (shorts)

  f32x4 zero = {0.f, 0.f, 0.f, 0.f};
  f32x4 acc[8][4];
#pragma unroll
  for (int mi = 0; mi < 8; ++mi)
#pragma unroll
    for (int ni = 0; ni < 4; ++ni) acc[mi][ni] = zero;

  // stage one 16KB half-tile: 2 gl_lds per wave (linear chunk->chunk)
  auto STAGE_H = [&](int isB, int h, int tile, int buf) {
    const uint4* src = isB ? Bg : Ag;
    const int rowblk = (isB ? n * 2 : My * 2) + h;
    const size_t c0 = ((size_t)(rowblk * 64 + z * NKT + tile)) * 1024 + w * 64 + lane;
    unsigned short* d = lds + isB * 32768 + buf * 16384 + h * 8192 + w * 512;
    __builtin_amdgcn_global_load_lds(
        (const __attribute__((address_space(1))) unsigned int*)(src + c0),
        (__attribute__((address_space(3))) unsigned int*)d, 16, 0, 0);
    __builtin_amdgcn_global_load_lds(
        (const __attribute__((address_space(1))) unsigned int*)(src + c0 + 512),
        (__attribute__((address_space(3))) unsigned int*)(d + 4096), 16, 0, 0);
  };

  bf16x8 af[4], bfr[4];

  // ---- prologue: tile0 (4 halves) -> buf0, B0(tile1) -> buf1; 10 loads ----
  STAGE_H(0, 0, 0, 0); STAGE_H(0, 1, 0, 0);
  STAGE_H(1, 0, 0, 0); STAGE_H(1, 1, 0, 0);
  STAGE_H(1, 0, 1, 1);
  asm volatile("s_waitcnt vmcnt(2)" ::: "memory");   // tile0 landed; B0(t1) in flight
  __builtin_amdgcn_sched_barrier(0);
  __builtin_amdgcn_s_barrier();

  // ---- main loop: iters 0..6, tiles (2it, 2it+1); stage t1-rest, t2, B0(t3) ----
  for (int it = 0; it < 7; ++it) {
    const int t1 = 2 * it + 1, t2 = 2 * it + 2, t3 = 2 * it + 3;
    PH(0, 0, 0, 1, 0, STAGE_H(1, 1, t1, 1));   // p0: +bf(ks0); stage B1(t1)
    PH(0, 1, 0, 0, 0, STAGE_H(0, 0, t1, 1));   // p1: stage A0(t1)
    PH(0, 0, 1, 1, 0, STAGE_H(0, 1, t1, 1));   // p2: +bf(ks1); stage A1(t1)
    PH(0, 1, 1, 0, 1, STAGE_H(1, 0, t2, 0));   // p3: stage B0(t2); vmcnt(2)
    PH(1, 0, 0, 1, 0, STAGE_H(0, 0, t2, 0));   // p4: stage A0(t2)
    PH(1, 1, 0, 0, 0, STAGE_H(0, 1, t2, 0));   // p5: stage A1(t2)
    PH(1, 0, 1, 1, 0, STAGE_H(1, 1, t2, 0));   // p6: stage B1(t2)
    PH(1, 1, 1, 0, 1, STAGE_H(1, 0, t3, 1));   // p7: stage B0(t3); vmcnt(2)
  }
  // ---- peeled iter 7: tiles 14,15; finish staging t1=15, no further stages ----
  PH(0, 0, 0, 1, 0, STAGE_H(1, 1, 15, 1));
  PH(0, 1, 0, 0, 0, STAGE_H(0, 0, 15, 1));
  PH(0, 0, 1, 1, 0, STAGE_H(0, 1, 15, 1));
  PH(0, 1, 1, 0, 2, (void)0);                  // vmcnt(0): tile15 fully landed
  PH(1, 0, 0, 1, 0, (void)0);
  PH(1, 1, 0, 0, 0, (void)0);
  PH(1, 0, 1, 1, 0, (void)0);
  PH(1, 1, 1, 0, 0, (void)0);

  // ---- epilogue: bf16 via per-wave LDS bounce (swizzled) -> uint4 line stores ----
  unsigned short* W = lds + w * 8192;    // 128 rows x 64 shorts per wave
#pragma unroll
  for (int mi = 0; mi < 8; ++mi)
#pragma unroll
    for (int ni = 0; ni < 4; ++ni) {
      int col = ni * 16 + arow;
      int c8 = col >> 3, cpos = col & 7;
#pragma unroll
      for (int r = 0; r < 4; ++r) {
        int row = mi * 16 + hi * 4 + r;
        W[row * 64 + ((c8 ^ (row & 7)) << 3) + cpos] = f2bf(acc[mi][ni][r]);
      }
    }
  const int rr = lane >> 3, cc = lane & 7;
#pragma unroll
  for (int it = 0; it < 16; ++it) {
    int row = it * 8 + rr;
    uint4 v = *(uint4*)&W[row * 64 + ((cc ^ (row & 7)) << 3)];
    size_t pr = ((size_t)z * B_ROWS + My * 256 + wm * 128 + row) * 512 + n * 256 + wn * 64 + cc * 8;
    *(uint4*)&P[pr] = v;
  }
}

// ---- pass 3: out = sum of bf16 partials, f32 (r6 verbatim) ----------------------
__global__ void reduce_kernel(const unsigned short* __restrict__ P, float* __restrict__ out) {
  size_t t = (size_t)blockIdx.x * 256 + threadIdx.x;
  const uint4* p = (const uint4*)P;
  const size_t stride = (size_t)B_ROWS * OUT_DIM / 8;
  float s[8] = {0, 0, 0, 0, 0, 0, 0, 0};
#pragma unroll
  for (int zz = 0; zz < ZSLICES; ++zz) {
    uint4 v = p[t + zz * stride];
    unsigned q[4] = {v.x, v.y, v.z, v.w};
#pragma unroll
    for (int j = 0; j < 4; ++j) {
      s[2 * j]     += __uint_as_float((q[j] & 0xffffu) << 16);
      s[2 * j + 1] += __uint_as_float(q[j] & 0xffff0000u);
    }
  }
  float4 o0 = {s[0], s[1], s[2], s[3]}, o1 = {s[4], s[5], s[6], s[7]};
  ((float4*)out)[t * 2]     = o0;
  ((float4*)out)[t * 2 + 1] = o1;
}

// ---- fallback -------------------------------------------------------------------
__global__ void naive_kernel(const float* __restrict__ x, const float* __restrict__ c,
                             float* __restrict__ out) {
  __shared__ float bas[IN_DIM * NDEG];
  int b = blockIdx.x;
  for (int i = threadIdx.x; i < IN_DIM; i += 256) {
    float t = tanhf(x[(size_t)b * IN_DIM + i]);
    float L[NDEG];
    laguerre8(t, L);
#pragma unroll
    for (int d = 0; d < NDEG; ++d) bas[i * NDEG + d] = L[d];
  }
  __syncthreads();
  for (int o = threadIdx.x; o < OUT_DIM; o += 256) {
    float acc = 0.f;
    for (int i = 0; i < IN_DIM; ++i) {
      const float* cp = c + ((size_t)i * OUT_DIM + o) * NDEG;
#pragma unroll
      for (int d = 0; d < NDEG; ++d) acc += bas[i * NDEG + d] * cp[d];
    }
    out[(size_t)b * OUT_DIM + o] = acc;
  }
}

extern "C" void kernel_launch(void* const* d_in, const int* in_sizes, int n_in,
                              void* d_out, int out_size, void* d_ws, size_t ws_size,
                              hipStream_t stream) {
  const float* x    = (const float*)d_in[0];
  const float* coef = (const float*)d_in[1];
  float* out = (float*)d_out;

  const size_t A_B  = (size_t)B_ROWS * KDIM * 2;              // 64 MiB
  const size_t P_B  = (size_t)ZSLICES * B_ROWS * OUT_DIM * 2; // 32 MiB
  const size_t BT_B = (size_t)OUT_DIM * KDIM * 2;             // 4 MiB

  if (ws_size >= A_B + P_B + BT_B) {   // 100 MiB — proven rounds 3-9
    unsigned short* Abuf = (unsigned short*)d_ws;
    unsigned short* Pp   = (unsigned short*)((char*)d_ws + A_B);
    unsigned short* Bt   = (unsigned short*)((char*)d_ws + A_B + P_B);
    prep_kernel<<<4096 + 1024, 256, 0, stream>>>(x, coef, Abuf, Bt);
    gemm_kernel<<<256, 512, 0, stream>>>(Abuf, Bt, Pp);
    reduce_kernel<<<(B_ROWS * OUT_DIM / 8) / 256, 256, 0, stream>>>(Pp, out);
  } else {
    naive_kernel<<<B_ROWS, 256, 0, stream>>>(x, coef, out);
  }
}

// Round 11
// 66.665 us; speedup vs baseline: 3.5938x; 1.1066x over previous
//
#include <hip/hip_runtime.h>

#define B_ROWS 8192
#define IN_DIM 512
#define OUT_DIM 512
#define NDEG 8                 // DEGREE+1
#define KDIM (IN_DIM * NDEG)   // 4096
#define ZSLICES 4
#define NKT 16                 // K-tiles (of 64) per z-slice

typedef short bf16x8 __attribute__((ext_vector_type(8)));
typedef float f32x4  __attribute__((ext_vector_type(4)));

__device__ __forceinline__ unsigned short f2bf(float f) {
  unsigned u = __float_as_uint(f);
  u += 0x7fffu + ((u >> 16) & 1u);   // RNE
  return (unsigned short)(u >> 16);
}

__device__ __forceinline__ void laguerre8(float t, float* L) {
  L[0] = 1.0f;
  L[1] = 1.5f - t;
#pragma unroll
  for (int k = 2; k < NDEG; ++k)
    L[k] = ((2.0f * (float)k - 0.5f - t) * L[k - 1] -
            ((float)k - 0.5f) * L[k - 2]) * (1.0f / (float)k);
}

__device__ __forceinline__ float ftanh(float x) {
  float e2 = __expf(2.0f * x);
  return (e2 - 1.0f) * (1.0f / (e2 + 1.0f));
}

__device__ __forceinline__ uint4 bpack(float xv) {
  float L[NDEG];
  laguerre8(ftanh(xv), L);
  uint4 v;
  v.x = (unsigned)f2bf(L[0]) | ((unsigned)f2bf(L[1]) << 16);
  v.y = (unsigned)f2bf(L[2]) | ((unsigned)f2bf(L[3]) << 16);
  v.z = (unsigned)f2bf(L[4]) | ((unsigned)f2bf(L[5]) << 16);
  v.w = (unsigned)f2bf(L[6]) | ((unsigned)f2bf(L[7]) << 16);
  return v;
}

// Brick layout (A and B identical; SQ_LDS_BANK_CONFLICT==0 verified r5/r6):
// 128-row x 64-k half-tiles of 16B chunks:
//   chunk = (rowblk*64 + ktile)*1024 + (rb>>6)*512 + (rb&63)*8 + (c ^ (rb&7))

// ---- pass 1: basis -> A bricks | coeffs -> Bt bricks (r6 version — fastest) -----
// A-branch: coalesced x reads; writes are 8x128B full-line segments per wave.
__global__ void prep_kernel(const float* __restrict__ x, const float* __restrict__ cf,
                            unsigned short* __restrict__ A, unsigned short* __restrict__ Bt) {
  int g = blockIdx.x;
  if (g < (B_ROWS * IN_DIM) / 256) {
    int idx = g * 256 + threadIdx.x;
    int b = idx >> 9, i = idx & 511;     // k = i*8 + d
    uint4 v = bpack(x[idx]);
    int h = b >> 7, rb = b & 127, t = i >> 3, c = i & 7;
    size_t chunk = ((size_t)(h * 64 + t)) * 1024 + (rb >> 6) * 512 + (rb & 63) * 8 + (c ^ (rb & 7));
    ((uint4*)A)[chunk] = v;
  } else {
    int idx = (g - (B_ROWS * IN_DIM) / 256) * 256 + threadIdx.x;   // i*512 + o
    int i = idx >> 9, o = idx & 511;
    const float4* cp = (const float4*)(cf + (size_t)idx * 8);
    float4 c0 = cp[0], c1 = cp[1];
    uint4 v;
    v.x = (unsigned)f2bf(c0.x) | ((unsigned)f2bf(c0.y) << 16);
    v.y = (unsigned)f2bf(c0.z) | ((unsigned)f2bf(c0.w) << 16);
    v.z = (unsigned)f2bf(c1.x) | ((unsigned)f2bf(c1.y) << 16);
    v.w = (unsigned)f2bf(c1.z) | ((unsigned)f2bf(c1.w) << 16);
    int h = o >> 7, rb = o & 127, t = i >> 3, c = i & 7;
    size_t chunk = ((size_t)(h * 64 + t)) * 1024 + (rb >> 6) * 512 + (rb & 63) * 8 + (c ^ (rb & 7));
    ((uint4*)Bt)[chunk] = v;
  }
}

// ---- pass 2: GEMM 256x256, 8-phase, barrier-thinned ------------------------------
// Phase = {ds_reads; OPEN barrier; stage-issue; lgkm0; 16 MFMA; [vmcnt+CLOSE bar]}.
// Closing barriers ONLY at p3/p7 (the vmcnt publication points). Stage issued
// AFTER the opening barrier => prev-phase reads of the target region are complete
// (reader's lgkmcnt(0) precedes its arrival at that barrier). vmcnt ledger = r6's.

#define PH(buf, mq, ks, LOADBF, VMW, ...)                                          \
  {                                                                                \
    const unsigned short* Ab_ = lds + (buf)*16384 + wm*8192 + (mq)*4096 + arow*64; \
    _Pragma("unroll") for (int m4 = 0; m4 < 4; ++m4)                               \
      af[m4] = *(const bf16x8*)(Ab_ + m4*1024 + (e ^ ((ks)*32)));                  \
    if (LOADBF) {                                                                  \
      const unsigned short* Bb_ = lds + 32768 + (buf)*16384 + (wn>>1)*8192         \
                                  + (wn&1)*4096 + arow*64;                         \
      _Pragma("unroll") for (int ni = 0; ni < 4; ++ni)                             \
        bfr[ni] = *(const bf16x8*)(Bb_ + ni*1024 + (e ^ ((ks)*32)));               \
    }                                                                              \
    __builtin_amdgcn_s_barrier();        /* open: prev-phase reads complete */     \
    __VA_ARGS__;                         /* stage-issue (safe after barrier) */    \
    asm volatile("s_waitcnt lgkmcnt(0)" ::: "memory");                             \
    __builtin_amdgcn_sched_barrier(0);                                             \
    __builtin_amdgcn_s_setprio(1);                                                 \
    _Pragma("unroll") for (int m4 = 0; m4 < 4; ++m4)                               \
      _Pragma("unroll") for (int ni = 0; ni < 4; ++ni)                             \
        acc[(mq)*4+m4][ni] = __builtin_amdgcn_mfma_f32_16x16x32_bf16(              \
            af[m4], bfr[ni], acc[(mq)*4+m4][ni], 0, 0, 0);                         \
    __builtin_amdgcn_s_setprio(0);                                                 \
    if ((VMW) == 1) { asm volatile("s_waitcnt vmcnt(2)" ::: "memory");             \
                      __builtin_amdgcn_sched_barrier(0);                           \
                      __builtin_amdgcn_s_barrier(); }   /* publish landings */     \
    if ((VMW) == 2) { asm volatile("s_waitcnt vmcnt(0)" ::: "memory");             \
                      __builtin_amdgcn_sched_barrier(0);                           \
                      __builtin_amdgcn_s_barrier(); }                              \
  }

__global__ __launch_bounds__(512, 2) void gemm_kernel(const unsigned short* __restrict__ A,
                                                      const unsigned short* __restrict__ Bt,
                                                      unsigned short* __restrict__ P) {
  __shared__ unsigned short lds[65536];   // 128 KB: A ring 64 KB | B ring 64 KB

  const int tid = threadIdx.x;
  const int lane = tid & 63;
  const int w = tid >> 6;
  const int wm = w >> 2, wn = w & 3;

  // bijective decode, A-panel sharers co-XCD
  const int g = blockIdx.x;               // 0..255
  const int j0 = g >> 3, xx = g & 7;
  const int My = ((j0 >> 3) << 3) | xx;   // 0..31
  const int n = (j0 >> 2) & 1;            // 0..1
  const int z = j0 & 3;                   // 0..3

  const uint4* Ag = (const uint4*)A;
  const uint4* Bg = (const uint4*)Bt;

  const int arow = lane & 15, hi = lane >> 4;
  const int e = (hi ^ (arow & 7)) * 8;    // swizzled chunk offset (shorts)

  f32x4 zero = {0.f, 0.f, 0.f, 0.f};
  f32x4 acc[8][4];
#pragma unroll
  for (int mi = 0; mi < 8; ++mi)
#pragma unroll
    for (int ni = 0; ni < 4; ++ni) acc[mi][ni] = zero;

  // stage one 16KB half-tile: 2 gl_lds per wave (linear chunk->chunk)
  auto STAGE_H = [&](int isB, int h, int tile, int buf) {
    const uint4* src = isB ? Bg : Ag;
    const int rowblk = (isB ? n * 2 : My * 2) + h;
    const size_t c0 = ((size_t)(rowblk * 64 + z * NKT + tile)) * 1024 + w * 64 + lane;
    unsigned short* d = lds + isB * 32768 + buf * 16384 + h * 8192 + w * 512;
    __builtin_amdgcn_global_load_lds(
        (const __attribute__((address_space(1))) unsigned int*)(src + c0),
        (__attribute__((address_space(3))) unsigned int*)d, 16, 0, 0);
    __builtin_amdgcn_global_load_lds(
        (const __attribute__((address_space(1))) unsigned int*)(src + c0 + 512),
        (__attribute__((address_space(3))) unsigned int*)(d + 4096), 16, 0, 0);
  };

  bf16x8 af[4], bfr[4];

  // ---- prologue: tile0 (4 halves) -> buf0, B0(tile1) -> buf1; 10 loads ----
  STAGE_H(0, 0, 0, 0); STAGE_H(0, 1, 0, 0);
  STAGE_H(1, 0, 0, 0); STAGE_H(1, 1, 0, 0);
  STAGE_H(1, 0, 1, 1);
  asm volatile("s_waitcnt vmcnt(2)" ::: "memory");   // tile0 landed; B0(t1) in flight
  __builtin_amdgcn_sched_barrier(0);
  __builtin_amdgcn_s_barrier();                      // publish tile0

  // ---- main loop: iters 0..6, tiles (2it, 2it+1); stage t1-rest, t2, B0(t3) ----
  for (int it = 0; it < 7; ++it) {
    const int t1 = 2 * it + 1, t2 = 2 * it + 2, t3 = 2 * it + 3;
    PH(0, 0, 0, 1, 0, STAGE_H(1, 1, t1, 1));   // p0: +bf(ks0); stage B1(t1)
    PH(0, 1, 0, 0, 0, STAGE_H(0, 0, t1, 1));   // p1: stage A0(t1)
    PH(0, 0, 1, 1, 0, STAGE_H(0, 1, t1, 1));   // p2: +bf(ks1); stage A1(t1)
    PH(0, 1, 1, 0, 1, STAGE_H(1, 0, t2, 0));   // p3: stage B0(t2); vmcnt(2)+close
    PH(1, 0, 0, 1, 0, STAGE_H(0, 0, t2, 0));   // p4: stage A0(t2)
    PH(1, 1, 0, 0, 0, STAGE_H(0, 1, t2, 0));   // p5: stage A1(t2)
    PH(1, 0, 1, 1, 0, STAGE_H(1, 1, t2, 0));   // p6: stage B1(t2)
    PH(1, 1, 1, 0, 1, STAGE_H(1, 0, t3, 1));   // p7: stage B0(t3); vmcnt(2)+close
  }
  // ---- peeled iter 7: tiles 14,15; finish staging t1=15, no further stages ----
  PH(0, 0, 0, 1, 0, STAGE_H(1, 1, 15, 1));
  PH(0, 1, 0, 0, 0, STAGE_H(0, 0, 15, 1));
  PH(0, 0, 1, 1, 0, STAGE_H(0, 1, 15, 1));
  PH(0, 1, 1, 0, 2, (void)0);                  // vmcnt(0)+close: tile15 landed
  PH(1, 0, 0, 1, 0, (void)0);
  PH(1, 1, 0, 0, 0, (void)0);
  PH(1, 0, 1, 1, 0, (void)0);
  PH(1, 1, 1, 0, 0, (void)0);
  __syncthreads();                             // all reads done before LDS reuse

  // ---- epilogue: bf16 via per-wave LDS bounce (swizzled) -> uint4 line stores ----
  unsigned short* W = lds + w * 8192;    // 128 rows x 64 shorts per wave
#pragma unroll
  for (int mi = 0; mi < 8; ++mi)
#pragma unroll
    for (int ni = 0; ni < 4; ++ni) {
      int col = ni * 16 + arow;
      int c8 = col >> 3, cpos = col & 7;
#pragma unroll
      for (int r = 0; r < 4; ++r) {
        int row = mi * 16 + hi * 4 + r;
        W[row * 64 + ((c8 ^ (row & 7)) << 3) + cpos] = f2bf(acc[mi][ni][r]);
      }
    }
  const int rr = lane >> 3, cc = lane & 7;
#pragma unroll
  for (int it = 0; it < 16; ++it) {
    int row = it * 8 + rr;
    uint4 v = *(uint4*)&W[row * 64 + ((cc ^ (row & 7)) << 3)];
    size_t pr = ((size_t)z * B_ROWS + My * 256 + wm * 128 + row) * 512 + n * 256 + wn * 64 + cc * 8;
    *(uint4*)&P[pr] = v;
  }
}

// ---- pass 3: out = sum of bf16 partials, f32 (r6 verbatim) ----------------------
__global__ void reduce_kernel(const unsigned short* __restrict__ P, float* __restrict__ out) {
  size_t t = (size_t)blockIdx.x * 256 + threadIdx.x;
  const uint4* p = (const uint4*)P;
  const size_t stride = (size_t)B_ROWS * OUT_DIM / 8;
  float s[8] = {0, 0, 0, 0, 0, 0, 0, 0};
#pragma unroll
  for (int zz = 0; zz < ZSLICES; ++zz) {
    uint4 v = p[t + zz * stride];
    unsigned q[4] = {v.x, v.y, v.z, v.w};
#pragma unroll
    for (int j = 0; j < 4; ++j) {
      s[2 * j]     += __uint_as_float((q[j] & 0xffffu) << 16);
      s[2 * j + 1] += __uint_as_float(q[j] & 0xffff0000u);
    }
  }
  float4 o0 = {s[0], s[1], s[2], s[3]}, o1 = {s[4], s[5], s[6], s[7]};
  ((float4*)out)[t * 2]     = o0;
  ((float4*)out)[t * 2 + 1] = o1;
}

// ---- fallback -------------------------------------------------------------------
__global__ void naive_kernel(const float* __restrict__ x, const float* __restrict__ c,
                             float* __restrict__ out) {
  __shared__ float bas[IN_DIM * NDEG];
  int b = blockIdx.x;
  for (int i = threadIdx.x; i < IN_DIM; i += 256) {
    float t = tanhf(x[(size_t)b * IN_DIM + i]);
    float L[NDEG];
    laguerre8(t, L);
#pragma unroll
    for (int d = 0; d < NDEG; ++d) bas[i * NDEG + d] = L[d];
  }
  __syncthreads();
  for (int o = threadIdx.x; o < OUT_DIM; o += 256) {
    float acc = 0.f;
    for (int i = 0; i < IN_DIM; ++i) {
      const float* cp = c + ((size_t)i * OUT_DIM + o) * NDEG;
#pragma unroll
      for (int d = 0; d < NDEG; ++d) acc += bas[i * NDEG + d] * cp[d];
    }
    out[(size_t)b * OUT_DIM + o] = acc;
  }
}

extern "C" void kernel_launch(void* const* d_in, const int* in_sizes, int n_in,
                              void* d_out, int out_size, void* d_ws, size_t ws_size,
                              hipStream_t stream) {
  const float* x    = (const float*)d_in[0];
  const float* coef = (const float*)d_in[1];
  float* out = (float*)d_out;

  const size_t A_B  = (size_t)B_ROWS * KDIM * 2;              // 64 MiB
  const size_t P_B  = (size_t)ZSLICES * B_ROWS * OUT_DIM * 2; // 32 MiB
  const size_t BT_B = (size_t)OUT_DIM * KDIM * 2;             // 4 MiB

  if (ws_size >= A_B + P_B + BT_B) {   // 100 MiB — proven rounds 3-10
    unsigned short* Abuf = (unsigned short*)d_ws;
    unsigned short* Pp   = (unsigned short*)((char*)d_ws + A_B);
    unsigned short* Bt   = (unsigned short*)((char*)d_ws + A_B + P_B);
    prep_kernel<<<(B_ROWS * IN_DIM) / 256 + (IN_DIM * OUT_DIM) / 256, 256, 0, stream>>>(x, coef, Abuf, Bt);
    gemm_kernel<<<256, 512, 0, stream>>>(Abuf, Bt, Pp);
    reduce_kernel<<<(B_ROWS * OUT_DIM / 8) / 256, 256, 0, stream>>>(Pp, out);
  } else {
    naive_kernel<<<B_ROWS, 256, 0, stream>>>(x, coef, out);
  }
}

// Round 12
// 66.630 us; speedup vs baseline: 3.5957x; 1.0005x over previous
//
#include <hip/hip_runtime.h>

#define B_ROWS 8192
#define IN_DIM 512
#define OUT_DIM 512
#define NDEG 8                 // DEGREE+1
#define KDIM (IN_DIM * NDEG)   // 4096
#define ZSLICES 4
#define NKT 16                 // K-tiles (of 64) per z-slice

typedef short bf16x8 __attribute__((ext_vector_type(8)));
typedef float f32x4  __attribute__((ext_vector_type(4)));

__device__ __forceinline__ unsigned short f2bf(float f) {
  unsigned u = __float_as_uint(f);
  u += 0x7fffu + ((u >> 16) & 1u);   // RNE
  return (unsigned short)(u >> 16);
}

__device__ __forceinline__ void laguerre8(float t, float* L) {
  L[0] = 1.0f;
  L[1] = 1.5f - t;
#pragma unroll
  for (int k = 2; k < NDEG; ++k)
    L[k] = ((2.0f * (float)k - 0.5f - t) * L[k - 1] -
            ((float)k - 0.5f) * L[k - 2]) * (1.0f / (float)k);
}

__device__ __forceinline__ float ftanh(float x) {
  float e2 = __expf(2.0f * x);
  return (e2 - 1.0f) * (1.0f / (e2 + 1.0f));
}

__device__ __forceinline__ uint4 bpack(float xv) {
  float L[NDEG];
  laguerre8(ftanh(xv), L);
  uint4 v;
  v.x = (unsigned)f2bf(L[0]) | ((unsigned)f2bf(L[1]) << 16);
  v.y = (unsigned)f2bf(L[2]) | ((unsigned)f2bf(L[3]) << 16);
  v.z = (unsigned)f2bf(L[4]) | ((unsigned)f2bf(L[5]) << 16);
  v.w = (unsigned)f2bf(L[6]) | ((unsigned)f2bf(L[7]) << 16);
  return v;
}

// Brick layout (A and B identical; SQ_LDS_BANK_CONFLICT==0 verified r5/r6):
// 128-row x 64-k half-tiles of 16B chunks:
//   chunk = (rowblk*64 + ktile)*1024 + (rb>>6)*512 + (rb&63)*8 + (c ^ (rb&7))

// ---- pass 1: basis -> A bricks | coeffs -> Bt bricks (r6 version — fastest) -----
__global__ void prep_kernel(const float* __restrict__ x, const float* __restrict__ cf,
                            unsigned short* __restrict__ A, unsigned short* __restrict__ Bt) {
  int g = blockIdx.x;
  if (g < (B_ROWS * IN_DIM) / 256) {
    int idx = g * 256 + threadIdx.x;
    int b = idx >> 9, i = idx & 511;     // k = i*8 + d
    uint4 v = bpack(x[idx]);
    int h = b >> 7, rb = b & 127, t = i >> 3, c = i & 7;
    size_t chunk = ((size_t)(h * 64 + t)) * 1024 + (rb >> 6) * 512 + (rb & 63) * 8 + (c ^ (rb & 7));
    ((uint4*)A)[chunk] = v;
  } else {
    int idx = (g - (B_ROWS * IN_DIM) / 256) * 256 + threadIdx.x;   // i*512 + o
    int i = idx >> 9, o = idx & 511;
    const float4* cp = (const float4*)(cf + (size_t)idx * 8);
    float4 c0 = cp[0], c1 = cp[1];
    uint4 v;
    v.x = (unsigned)f2bf(c0.x) | ((unsigned)f2bf(c0.y) << 16);
    v.y = (unsigned)f2bf(c0.z) | ((unsigned)f2bf(c0.w) << 16);
    v.z = (unsigned)f2bf(c1.x) | ((unsigned)f2bf(c1.y) << 16);
    v.w = (unsigned)f2bf(c1.z) | ((unsigned)f2bf(c1.w) << 16);
    int h = o >> 7, rb = o & 127, t = i >> 3, c = i & 7;
    size_t chunk = ((size_t)(h * 64 + t)) * 1024 + (rb >> 6) * 512 + (rb & 63) * 8 + (c ^ (rb & 7));
    ((uint4*)Bt)[chunk] = v;
  }
}

// ---- pass 2: GEMM 256x256, 8-phase, MINIMAL barriers -----------------------------
// Invariant: within each half-iteration (p0-p3 / p4-p7), ds_reads touch only
// buf[cur] and stages write only buf[cur^1] — disjoint, so no intra-half barrier
// needed. Exceptions: p3/p7's B0-stage targets the read-side buffer -> OPEN
// barrier kept there. Publication: p3/p7-close (counted vmcnt(2), r6 ledger:
// exactly the 8-oldest = next tile's loads drain; newest 2 stay in flight).
// sched_barrier(0) after every s_barrier pins reads/stages below the barrier.

#define PH(buf, mq, ks, LOADBF, OPEN, VMW, ...)                                    \
  {                                                                                \
    const unsigned short* Ab_ = lds + (buf)*16384 + wm*8192 + (mq)*4096 + arow*64; \
    _Pragma("unroll") for (int m4 = 0; m4 < 4; ++m4)                               \
      af[m4] = *(const bf16x8*)(Ab_ + m4*1024 + (e ^ ((ks)*32)));                  \
    if (LOADBF) {                                                                  \
      const unsigned short* Bb_ = lds + 32768 + (buf)*16384 + (wn>>1)*8192         \
                                  + (wn&1)*4096 + arow*64;                         \
      _Pragma("unroll") for (int ni = 0; ni < 4; ++ni)                             \
        bfr[ni] = *(const bf16x8*)(Bb_ + ni*1024 + (e ^ ((ks)*32)));               \
    }                                                                              \
    if (OPEN) { __builtin_amdgcn_s_barrier();                                      \
                __builtin_amdgcn_sched_barrier(0); }                               \
    __VA_ARGS__;                                                                   \
    asm volatile("s_waitcnt lgkmcnt(0)" ::: "memory");                             \
    __builtin_amdgcn_sched_barrier(0);                                             \
    __builtin_amdgcn_s_setprio(1);                                                 \
    _Pragma("unroll") for (int m4 = 0; m4 < 4; ++m4)                               \
      _Pragma("unroll") for (int ni = 0; ni < 4; ++ni)                             \
        acc[(mq)*4+m4][ni] = __builtin_amdgcn_mfma_f32_16x16x32_bf16(              \
            af[m4], bfr[ni], acc[(mq)*4+m4][ni], 0, 0, 0);                         \
    __builtin_amdgcn_s_setprio(0);                                                 \
    if ((VMW) == 1) { asm volatile("s_waitcnt vmcnt(2)" ::: "memory");             \
                      __builtin_amdgcn_sched_barrier(0);                           \
                      __builtin_amdgcn_s_barrier();                                \
                      __builtin_amdgcn_sched_barrier(0); }                         \
    if ((VMW) == 2) { asm volatile("s_waitcnt vmcnt(0)" ::: "memory");             \
                      __builtin_amdgcn_sched_barrier(0);                           \
                      __builtin_amdgcn_s_barrier();                                \
                      __builtin_amdgcn_sched_barrier(0); }                         \
  }

__global__ __launch_bounds__(512, 2) void gemm_kernel(const unsigned short* __restrict__ A,
                                                      const unsigned short* __restrict__ Bt,
                                                      unsigned short* __restrict__ P) {
  __shared__ unsigned short lds[65536];   // 128 KB: A ring 64 KB | B ring 64 KB

  const int tid = threadIdx.x;
  const int lane = tid & 63;
  const int w = tid >> 6;
  const int wm = w >> 2, wn = w & 3;

  // bijective decode, A-panel sharers co-XCD
  const int g = blockIdx.x;               // 0..255
  const int j0 = g >> 3, xx = g & 7;
  const int My = ((j0 >> 3) << 3) | xx;   // 0..31
  const int n = (j0 >> 2) & 1;            // 0..1
  const int z = j0 & 3;                   // 0..3

  const uint4* Ag = (const uint4*)A;
  const uint4* Bg = (const uint4*)Bt;

  const int arow = lane & 15, hi = lane >> 4;
  const int e = (hi ^ (arow & 7)) * 8;    // swizzled chunk offset (shorts)

  f32x4 zero = {0.f, 0.f, 0.f, 0.f};
  f32x4 acc[8][4];
#pragma unroll
  for (int mi = 0; mi < 8; ++mi)
#pragma unroll
    for (int ni = 0; ni < 4; ++ni) acc[mi][ni] = zero;

  // stage one 16KB half-tile: 2 gl_lds per wave (linear chunk->chunk)
  auto STAGE_H = [&](int isB, int h, int tile, int buf) {
    const uint4* src = isB ? Bg : Ag;
    const int rowblk = (isB ? n * 2 : My * 2) + h;
    const size_t c0 = ((size_t)(rowblk * 64 + z * NKT + tile)) * 1024 + w * 64 + lane;
    unsigned short* d = lds + isB * 32768 + buf * 16384 + h * 8192 + w * 512;
    __builtin_amdgcn_global_load_lds(
        (const __attribute__((address_space(1))) unsigned int*)(src + c0),
        (__attribute__((address_space(3))) unsigned int*)d, 16, 0, 0);
    __builtin_amdgcn_global_load_lds(
        (const __attribute__((address_space(1))) unsigned int*)(src + c0 + 512),
        (__attribute__((address_space(3))) unsigned int*)(d + 4096), 16, 0, 0);
  };

  bf16x8 af[4], bfr[4];

  // ---- prologue: tile0 (4 halves) -> buf0, B0(tile1) -> buf1; 10 loads ----
  STAGE_H(0, 0, 0, 0); STAGE_H(0, 1, 0, 0);
  STAGE_H(1, 0, 0, 0); STAGE_H(1, 1, 0, 0);
  STAGE_H(1, 0, 1, 1);
  asm volatile("s_waitcnt vmcnt(2)" ::: "memory");   // tile0 landed; B0(t1) in flight
  __builtin_amdgcn_sched_barrier(0);
  __builtin_amdgcn_s_barrier();                      // publish tile0
  __builtin_amdgcn_sched_barrier(0);

  // ---- main loop: iters 0..6, tiles (2it, 2it+1) ----
  // p0-p2: read buf0, stage buf1 (disjoint -> no barriers)
  // p3: OPEN (B0-stage hits read-side buf0) + vmcnt(2) close (publish t1)
  // p4-p6: read buf1, stage buf0 (disjoint)
  // p7: OPEN + vmcnt(2) close (publish t2)
  for (int it = 0; it < 7; ++it) {
    const int t1 = 2 * it + 1, t2 = 2 * it + 2, t3 = 2 * it + 3;
    PH(0, 0, 0, 1, 0, 0, STAGE_H(1, 1, t1, 1));   // p0: stage B1(t1)
    PH(0, 1, 0, 0, 0, 0, STAGE_H(0, 0, t1, 1));   // p1: stage A0(t1)
    PH(0, 0, 1, 1, 0, 0, STAGE_H(0, 1, t1, 1));   // p2: stage A1(t1)
    PH(0, 1, 1, 0, 1, 1, STAGE_H(1, 0, t2, 0));   // p3: OPEN; stage B0(t2); close
    PH(1, 0, 0, 1, 0, 0, STAGE_H(0, 0, t2, 0));   // p4: stage A0(t2)
    PH(1, 1, 0, 0, 0, 0, STAGE_H(0, 1, t2, 0));   // p5: stage A1(t2)
    PH(1, 0, 1, 1, 0, 0, STAGE_H(1, 1, t2, 0));   // p6: stage B1(t2)
    PH(1, 1, 1, 0, 1, 1, STAGE_H(1, 0, t3, 1));   // p7: OPEN; stage B0(t3); close
  }
  // ---- peeled iter 7: tiles 14,15; finish staging t1=15, no further stages ----
  PH(0, 0, 0, 1, 0, 0, STAGE_H(1, 1, 15, 1));
  PH(0, 1, 0, 0, 0, 0, STAGE_H(0, 0, 15, 1));
  PH(0, 0, 1, 1, 0, 0, STAGE_H(0, 1, 15, 1));
  PH(0, 1, 1, 0, 0, 2, (void)0);                  // vmcnt(0)+close: t15 landed
  PH(1, 0, 0, 1, 0, 0, (void)0);
  PH(1, 1, 0, 0, 0, 0, (void)0);
  PH(1, 0, 1, 1, 0, 0, (void)0);
  PH(1, 1, 1, 0, 0, 0, (void)0);
  __syncthreads();                                // all reads done before LDS reuse

  // ---- epilogue: bf16 via per-wave LDS bounce (swizzled) -> uint4 line stores ----
  unsigned short* W = lds + w * 8192;    // 128 rows x 64 shorts per wave
#pragma unroll
  for (int mi = 0; mi < 8; ++mi)
#pragma unroll
    for (int ni = 0; ni < 4; ++ni) {
      int col = ni * 16 + arow;
      int c8 = col >> 3, cpos = col & 7;
#pragma unroll
      for (int r = 0; r < 4; ++r) {
        int row = mi * 16 + hi * 4 + r;
        W[row * 64 + ((c8 ^ (row & 7)) << 3) + cpos] = f2bf(acc[mi][ni][r]);
      }
    }
  const int rr = lane >> 3, cc = lane & 7;
#pragma unroll
  for (int it = 0; it < 16; ++it) {
    int row = it * 8 + rr;
    uint4 v = *(uint4*)&W[row * 64 + ((cc ^ (row & 7)) << 3)];
    size_t pr = ((size_t)z * B_ROWS + My * 256 + wm * 128 + row) * 512 + n * 256 + wn * 64 + cc * 8;
    *(uint4*)&P[pr] = v;
  }
}

// ---- pass 3: out = sum of bf16 partials, f32 (r6 verbatim) ----------------------
__global__ void reduce_kernel(const unsigned short* __restrict__ P, float* __restrict__ out) {
  size_t t = (size_t)blockIdx.x * 256 + threadIdx.x;
  const uint4* p = (const uint4*)P;
  const size_t stride = (size_t)B_ROWS * OUT_DIM / 8;
  float s[8] = {0, 0, 0, 0, 0, 0, 0, 0};
#pragma unroll
  for (int zz = 0; zz < ZSLICES; ++zz) {
    uint4 v = p[t + zz * stride];
    unsigned q[4] = {v.x, v.y, v.z, v.w};
#pragma unroll
    for (int j = 0; j < 4; ++j) {
      s[2 * j]     += __uint_as_float((q[j] & 0xffffu) << 16);
      s[2 * j + 1] += __uint_as_float(q[j] & 0xffff0000u);
    }
  }
  float4 o0 = {s[0], s[1], s[2], s[3]}, o1 = {s[4], s[5], s[6], s[7]};
  ((float4*)out)[t * 2]     = o0;
  ((float4*)out)[t * 2 + 1] = o1;
}

// ---- fallback -------------------------------------------------------------------
__global__ void naive_kernel(const float* __restrict__ x, const float* __restrict__ c,
                             float* __restrict__ out) {
  __shared__ float bas[IN_DIM * NDEG];
  int b = blockIdx.x;
  for (int i = threadIdx.x; i < IN_DIM; i += 256) {
    float t = tanhf(x[(size_t)b * IN_DIM + i]);
    float L[NDEG];
    laguerre8(t, L);
#pragma unroll
    for (int d = 0; d < NDEG; ++d) bas[i * NDEG + d] = L[d];
  }
  __syncthreads();
  for (int o = threadIdx.x; o < OUT_DIM; o += 256) {
    float acc = 0.f;
    for (int i = 0; i < IN_DIM; ++i) {
      const float* cp = c + ((size_t)i * OUT_DIM + o) * NDEG;
#pragma unroll
      for (int d = 0; d < NDEG; ++d) acc += bas[i * NDEG + d] * cp[d];
    }
    out[(size_t)b * OUT_DIM + o] = acc;
  }
}

extern "C" void kernel_launch(void* const* d_in, const int* in_sizes, int n_in,
                              void* d_out, int out_size, void* d_ws, size_t ws_size,
                              hipStream_t stream) {
  const float* x    = (const float*)d_in[0];
  const float* coef = (const float*)d_in[1];
  float* out = (float*)d_out;

  const size_t A_B  = (size_t)B_ROWS * KDIM * 2;              // 64 MiB
  const size_t P_B  = (size_t)ZSLICES * B_ROWS * OUT_DIM * 2; // 32 MiB
  const size_t BT_B = (size_t)OUT_DIM * KDIM * 2;             // 4 MiB

  if (ws_size >= A_B + P_B + BT_B) {   // 100 MiB — proven rounds 3-11
    unsigned short* Abuf = (unsigned short*)d_ws;
    unsigned short* Pp   = (unsigned short*)((char*)d_ws + A_B);
    unsigned short* Bt   = (unsigned short*)((char*)d_ws + A_B + P_B);
    prep_kernel<<<(B_ROWS * IN_DIM) / 256 + (IN_DIM * OUT_DIM) / 256, 256, 0, stream>>>(x, coef, Abuf, Bt);
    gemm_kernel<<<256, 512, 0, stream>>>(Abuf, Bt, Pp);
    reduce_kernel<<<(B_ROWS * OUT_DIM / 8) / 256, 256, 0, stream>>>(Pp, out);
  } else {
    naive_kernel<<<B_ROWS, 256, 0, stream>>>(x, coef, out);
  }
}

// Round 13
// 66.149 us; speedup vs baseline: 3.6218x; 1.0073x over previous
//
#include <hip/hip_runtime.h>

#define B_ROWS 8192
#define IN_DIM 512
#define OUT_DIM 512
#define NDEG 8                 // DEGREE+1
#define KDIM (IN_DIM * NDEG)   // 4096
#define ZSLICES 4
#define NKT 16                 // K-tiles (of 64) per z-slice

typedef short bf16x8 __attribute__((ext_vector_type(8)));
typedef float f32x4  __attribute__((ext_vector_type(4)));

__device__ __forceinline__ unsigned short f2bf(float f) {
  unsigned u = __float_as_uint(f);
  u += 0x7fffu + ((u >> 16) & 1u);   // RNE
  return (unsigned short)(u >> 16);
}

__device__ __forceinline__ void laguerre8(float t, float* L) {
  L[0] = 1.0f;
  L[1] = 1.5f - t;
#pragma unroll
  for (int k = 2; k < NDEG; ++k)
    L[k] = ((2.0f * (float)k - 0.5f - t) * L[k - 1] -
            ((float)k - 0.5f) * L[k - 2]) * (1.0f / (float)k);
}

__device__ __forceinline__ float ftanh(float x) {
  float e2 = __expf(2.0f * x);
  return (e2 - 1.0f) * (1.0f / (e2 + 1.0f));
}

__device__ __forceinline__ uint4 bpack(float xv) {
  float L[NDEG];
  laguerre8(ftanh(xv), L);
  uint4 v;
  v.x = (unsigned)f2bf(L[0]) | ((unsigned)f2bf(L[1]) << 16);
  v.y = (unsigned)f2bf(L[2]) | ((unsigned)f2bf(L[3]) << 16);
  v.z = (unsigned)f2bf(L[4]) | ((unsigned)f2bf(L[5]) << 16);
  v.w = (unsigned)f2bf(L[6]) | ((unsigned)f2bf(L[7]) << 16);
  return v;
}

// Brick layout (A and B identical; SQ_LDS_BANK_CONFLICT==0 verified r5/r6):
// 128-row x 64-k half-tiles of 16B chunks:
//   chunk = (rowblk*64 + ktile)*1024 + (rb>>6)*512 + (rb&63)*8 + (c ^ (rb&7))

// ---- pass 1: basis -> A bricks | coeffs -> Bt bricks (r6 version — fastest) -----
__global__ void prep_kernel(const float* __restrict__ x, const float* __restrict__ cf,
                            unsigned short* __restrict__ A, unsigned short* __restrict__ Bt) {
  int g = blockIdx.x;
  if (g < (B_ROWS * IN_DIM) / 256) {
    int idx = g * 256 + threadIdx.x;
    int b = idx >> 9, i = idx & 511;     // k = i*8 + d
    uint4 v = bpack(x[idx]);
    int h = b >> 7, rb = b & 127, t = i >> 3, c = i & 7;
    size_t chunk = ((size_t)(h * 64 + t)) * 1024 + (rb >> 6) * 512 + (rb & 63) * 8 + (c ^ (rb & 7));
    ((uint4*)A)[chunk] = v;
  } else {
    int idx = (g - (B_ROWS * IN_DIM) / 256) * 256 + threadIdx.x;   // i*512 + o
    int i = idx >> 9, o = idx & 511;
    const float4* cp = (const float4*)(cf + (size_t)idx * 8);
    float4 c0 = cp[0], c1 = cp[1];
    uint4 v;
    v.x = (unsigned)f2bf(c0.x) | ((unsigned)f2bf(c0.y) << 16);
    v.y = (unsigned)f2bf(c0.z) | ((unsigned)f2bf(c0.w) << 16);
    v.z = (unsigned)f2bf(c1.x) | ((unsigned)f2bf(c1.y) << 16);
    v.w = (unsigned)f2bf(c1.z) | ((unsigned)f2bf(c1.w) << 16);
    int h = o >> 7, rb = o & 127, t = i >> 3, c = i & 7;
    size_t chunk = ((size_t)(h * 64 + t)) * 1024 + (rb >> 6) * 512 + (rb & 63) * 8 + (c ^ (rb & 7));
    ((uint4*)Bt)[chunk] = v;
  }
}

// ---- pass 2: GEMM 256x256, 8-phase, cross-phase register pipeline ---------------
// Change vs r12 (same barrier/vmcnt ledger, proven): fragment ds_reads are issued
// ONE PHASE EARLY into alternate register sets (afA/afB, bfA/bfB); per-phase
// lgkmcnt(0) drains removed — compiler emits exact counted lgkm waits before each
// MFMA's first use. sched_barrier(0) pins {loads,stage} above each MFMA cluster.
// Hazards: early reads only touch the published buffer; every B-region read
// completes (its MFMA precedes the p3/p7 OPEN barrier) before B0-stage overwrites;
// A-region reads outstanding at the barrier are disjoint from the B0 write.

#define SB __builtin_amdgcn_sched_barrier(0)

#define LDA(SET, buf, mq, ks)                                                      \
  { const unsigned short* Ab_ = lds + (buf)*16384 + wm*8192 + (mq)*4096 + arow*64; \
    _Pragma("unroll") for (int m4 = 0; m4 < 4; ++m4)                               \
      SET[m4] = *(const bf16x8*)(Ab_ + m4*1024 + (e ^ ((ks)*32))); }

#define LDB_(SET, buf, ks)                                                         \
  { const unsigned short* Bb_ = lds + 32768 + (buf)*16384 + (wn>>1)*8192           \
                                + (wn&1)*4096 + arow*64;                           \
    _Pragma("unroll") for (int ni = 0; ni < 4; ++ni)                               \
      SET[ni] = *(const bf16x8*)(Bb_ + ni*1024 + (e ^ ((ks)*32))); }

#define MM(ASET, BSET, mq)                                                         \
  { __builtin_amdgcn_s_setprio(1);                                                 \
    _Pragma("unroll") for (int m4 = 0; m4 < 4; ++m4)                               \
      _Pragma("unroll") for (int ni = 0; ni < 4; ++ni)                             \
        acc[(mq)*4+m4][ni] = __builtin_amdgcn_mfma_f32_16x16x32_bf16(              \
            ASET[m4], BSET[ni], acc[(mq)*4+m4][ni], 0, 0, 0);                      \
    __builtin_amdgcn_s_setprio(0); }

__global__ __launch_bounds__(512, 2) void gemm_kernel(const unsigned short* __restrict__ A,
                                                      const unsigned short* __restrict__ Bt,
                                                      unsigned short* __restrict__ P) {
  __shared__ unsigned short lds[65536];   // 128 KB: A ring 64 KB | B ring 64 KB

  const int tid = threadIdx.x;
  const int lane = tid & 63;
  const int w = tid >> 6;
  const int wm = w >> 2, wn = w & 3;

  // bijective decode, A-panel sharers co-XCD
  const int g = blockIdx.x;               // 0..255
  const int j0 = g >> 3, xx = g & 7;
  const int My = ((j0 >> 3) << 3) | xx;   // 0..31
  const int n = (j0 >> 2) & 1;            // 0..1
  const int z = j0 & 3;                   // 0..3

  const uint4* Ag = (const uint4*)A;
  const uint4* Bg = (const uint4*)Bt;

  const int arow = lane & 15, hi = lane >> 4;
  const int e = (hi ^ (arow & 7)) * 8;    // swizzled chunk offset (shorts)

  f32x4 zero = {0.f, 0.f, 0.f, 0.f};
  f32x4 acc[8][4];
#pragma unroll
  for (int mi = 0; mi < 8; ++mi)
#pragma unroll
    for (int ni = 0; ni < 4; ++ni) acc[mi][ni] = zero;

  // stage one 16KB half-tile: 2 gl_lds per wave (linear chunk->chunk)
  auto STAGE_H = [&](int isB, int h, int tile, int buf) {
    const uint4* src = isB ? Bg : Ag;
    const int rowblk = (isB ? n * 2 : My * 2) + h;
    const size_t c0 = ((size_t)(rowblk * 64 + z * NKT + tile)) * 1024 + w * 64 + lane;
    unsigned short* d = lds + isB * 32768 + buf * 16384 + h * 8192 + w * 512;
    __builtin_amdgcn_global_load_lds(
        (const __attribute__((address_space(1))) unsigned int*)(src + c0),
        (__attribute__((address_space(3))) unsigned int*)d, 16, 0, 0);
    __builtin_amdgcn_global_load_lds(
        (const __attribute__((address_space(1))) unsigned int*)(src + c0 + 512),
        (__attribute__((address_space(3))) unsigned int*)(d + 4096), 16, 0, 0);
  };

  bf16x8 afA[4], afB[4], bfA[4], bfB[4];

  // ---- prologue: tile0 (4 halves) -> buf0, B0(tile1) -> buf1; 10 loads ----
  STAGE_H(0, 0, 0, 0); STAGE_H(0, 1, 0, 0);
  STAGE_H(1, 0, 0, 0); STAGE_H(1, 1, 0, 0);
  STAGE_H(1, 0, 1, 1);
  asm volatile("s_waitcnt vmcnt(2)" ::: "memory");   // tile0 landed; B0(t1) in flight
  SB;
  __builtin_amdgcn_s_barrier();                      // publish tile0
  SB;
  LDA(afA, 0, 0, 0); LDB_(bfA, 0, 0);                // issue P0 reads

  // ---- main loop: iters 0..6, tiles (2it, 2it+1) ----
  for (int it = 0; it < 7; ++it) {
    const int t1 = 2 * it + 1, t2 = 2 * it + 2, t3 = 2 * it + 3;
    // ph0: issue P1; stage B1(t1); MFMA P0
    LDA(afB, 0, 1, 0); STAGE_H(1, 1, t1, 1); SB; MM(afA, bfA, 0);
    // ph1: issue P2 (af+bf ks1); stage A0(t1); MFMA P1
    LDA(afA, 0, 0, 1); LDB_(bfB, 0, 1); STAGE_H(0, 0, t1, 1); SB; MM(afB, bfA, 1);
    // ph2: issue P3; stage A1(t1); MFMA P2
    LDA(afB, 0, 1, 1); STAGE_H(0, 1, t1, 1); SB; MM(afA, bfB, 0);
    // ph3: OPEN; stage B0(t2)->buf0; MFMA P3; vmcnt(2); CLOSE; issue P4
    __builtin_amdgcn_s_barrier(); SB;
    STAGE_H(1, 0, t2, 0); SB;
    MM(afB, bfB, 1);
    asm volatile("s_waitcnt vmcnt(2)" ::: "memory"); SB;
    __builtin_amdgcn_s_barrier(); SB;
    LDA(afA, 1, 0, 0); LDB_(bfA, 1, 0);
    // ph4: issue P5; stage A0(t2); MFMA P4
    LDA(afB, 1, 1, 0); STAGE_H(0, 0, t2, 0); SB; MM(afA, bfA, 0);
    // ph5: issue P6; stage A1(t2); MFMA P5
    LDA(afA, 1, 0, 1); LDB_(bfB, 1, 1); STAGE_H(0, 1, t2, 0); SB; MM(afB, bfA, 1);
    // ph6: issue P7; stage B1(t2); MFMA P6
    LDA(afB, 1, 1, 1); STAGE_H(1, 1, t2, 0); SB; MM(afA, bfB, 0);
    // ph7: OPEN; stage B0(t3)->buf1; MFMA P7; vmcnt(2); CLOSE; issue next P0
    __builtin_amdgcn_s_barrier(); SB;
    STAGE_H(1, 0, t3, 1); SB;
    MM(afB, bfB, 1);
    asm volatile("s_waitcnt vmcnt(2)" ::: "memory"); SB;
    __builtin_amdgcn_s_barrier(); SB;
    LDA(afA, 0, 0, 0); LDB_(bfA, 0, 0);
  }
  // ---- peeled iter 7: tiles 14,15; finish staging t=15, then drain ----
  LDA(afB, 0, 1, 0); STAGE_H(1, 1, 15, 1); SB; MM(afA, bfA, 0);
  LDA(afA, 0, 0, 1); LDB_(bfB, 0, 1); STAGE_H(0, 0, 15, 1); SB; MM(afB, bfA, 1);
  LDA(afB, 0, 1, 1); STAGE_H(0, 1, 15, 1); SB; MM(afA, bfB, 0);
  MM(afB, bfB, 1);
  asm volatile("s_waitcnt vmcnt(0)" ::: "memory"); SB;   // tile15 fully landed
  __builtin_amdgcn_s_barrier(); SB;
  LDA(afA, 1, 0, 0); LDB_(bfA, 1, 0);
  LDA(afB, 1, 1, 0); SB; MM(afA, bfA, 0);
  LDA(afA, 1, 0, 1); LDB_(bfB, 1, 1); SB; MM(afB, bfA, 1);
  LDA(afB, 1, 1, 1); SB; MM(afA, bfB, 0);
  MM(afB, bfB, 1);
  __syncthreads();                                // all reads done before LDS reuse

  // ---- epilogue: bf16 via per-wave LDS bounce (swizzled) -> uint4 line stores ----
  unsigned short* W = lds + w * 8192;    // 128 rows x 64 shorts per wave
#pragma unroll
  for (int mi = 0; mi < 8; ++mi)
#pragma unroll
    for (int ni = 0; ni < 4; ++ni) {
      int col = ni * 16 + arow;
      int c8 = col >> 3, cpos = col & 7;
#pragma unroll
      for (int r = 0; r < 4; ++r) {
        int row = mi * 16 + hi * 4 + r;
        W[row * 64 + ((c8 ^ (row & 7)) << 3) + cpos] = f2bf(acc[mi][ni][r]);
      }
    }
  const int rr = lane >> 3, cc = lane & 7;
#pragma unroll
  for (int it = 0; it < 16; ++it) {
    int row = it * 8 + rr;
    uint4 v = *(uint4*)&W[row * 64 + ((cc ^ (row & 7)) << 3)];
    size_t pr = ((size_t)z * B_ROWS + My * 256 + wm * 128 + row) * 512 + n * 256 + wn * 64 + cc * 8;
    *(uint4*)&P[pr] = v;
  }
}

// ---- pass 3: out = sum of bf16 partials, f32 (r6 verbatim) ----------------------
__global__ void reduce_kernel(const unsigned short* __restrict__ P, float* __restrict__ out) {
  size_t t = (size_t)blockIdx.x * 256 + threadIdx.x;
  const uint4* p = (const uint4*)P;
  const size_t stride = (size_t)B_ROWS * OUT_DIM / 8;
  float s[8] = {0, 0, 0, 0, 0, 0, 0, 0};
#pragma unroll
  for (int zz = 0; zz < ZSLICES; ++zz) {
    uint4 v = p[t + zz * stride];
    unsigned q[4] = {v.x, v.y, v.z, v.w};
#pragma unroll
    for (int j = 0; j < 4; ++j) {
      s[2 * j]     += __uint_as_float((q[j] & 0xffffu) << 16);
      s[2 * j + 1] += __uint_as_float(q[j] & 0xffff0000u);
    }
  }
  float4 o0 = {s[0], s[1], s[2], s[3]}, o1 = {s[4], s[5], s[6], s[7]};
  ((float4*)out)[t * 2]     = o0;
  ((float4*)out)[t * 2 + 1] = o1;
}

// ---- fallback -------------------------------------------------------------------
__global__ void naive_kernel(const float* __restrict__ x, const float* __restrict__ c,
                             float* __restrict__ out) {
  __shared__ float bas[IN_DIM * NDEG];
  int b = blockIdx.x;
  for (int i = threadIdx.x; i < IN_DIM; i += 256) {
    float t = tanhf(x[(size_t)b * IN_DIM + i]);
    float L[NDEG];
    laguerre8(t, L);
#pragma unroll
    for (int d = 0; d < NDEG; ++d) bas[i * NDEG + d] = L[d];
  }
  __syncthreads();
  for (int o = threadIdx.x; o < OUT_DIM; o += 256) {
    float acc = 0.f;
    for (int i = 0; i < IN_DIM; ++i) {
      const float* cp = c + ((size_t)i * OUT_DIM + o) * NDEG;
#pragma unroll
      for (int d = 0; d < NDEG; ++d) acc += bas[i * NDEG + d] * cp[d];
    }
    out[(size_t)b * OUT_DIM + o] = acc;
  }
}

extern "C" void kernel_launch(void* const* d_in, const int* in_sizes, int n_in,
                              void* d_out, int out_size, void* d_ws, size_t ws_size,
                              hipStream_t stream) {
  const float* x    = (const float*)d_in[0];
  const float* coef = (const float*)d_in[1];
  float* out = (float*)d_out;

  const size_t A_B  = (size_t)B_ROWS * KDIM * 2;              // 64 MiB
  const size_t P_B  = (size_t)ZSLICES * B_ROWS * OUT_DIM * 2; // 32 MiB
  const size_t BT_B = (size_t)OUT_DIM * KDIM * 2;             // 4 MiB

  if (ws_size >= A_B + P_B + BT_B) {   // 100 MiB — proven rounds 3-12
    unsigned short* Abuf = (unsigned short*)d_ws;
    unsigned short* Pp   = (unsigned short*)((char*)d_ws + A_B);
    unsigned short* Bt   = (unsigned short*)((char*)d_ws + A_B + P_B);
    prep_kernel<<<(B_ROWS * IN_DIM) / 256 + (IN_DIM * OUT_DIM) / 256, 256, 0, stream>>>(x, coef, Abuf, Bt);
    gemm_kernel<<<256, 512, 0, stream>>>(Abuf, Bt, Pp);
    reduce_kernel<<<(B_ROWS * OUT_DIM / 8) / 256, 256, 0, stream>>>(Pp, out);
  } else {
    naive_kernel<<<B_ROWS, 256, 0, stream>>>(x, coef, out);
  }
}